// Round 9
// baseline (8855.907 us; speedup 1.0000x reference)
//
#include <hip/hip_runtime.h>
#include <math.h>

#define B_ 16
#define N_ 2048
#define M_ 2048
#define ITERS_ 100
#define RCH_ 32
#define NCH_ (N_ / RCH_)            // 64 chunks
// (1/eps)*log2(e), eps = 0.1
#define SCALE_ 14.426950408889634f
// u16 fixed-point C: Chat = c16/65535
#define KQ_ (SCALE_ / 65535.0f)

typedef float f4 __attribute__((ext_vector_type(4)));
typedef unsigned short u16x8 __attribute__((ext_vector_type(8)));

static __device__ __forceinline__ f4 exp2v(f4 x) {
  return f4{exp2f(x.x), exp2f(x.y), exp2f(x.z), exp2f(x.w)};
}
static __device__ __forceinline__ f4 log2v(f4 x) {
  return f4{log2f(x.x), log2f(x.y), log2f(x.z), log2f(x.w)};
}
static __device__ __forceinline__ float hsum(f4 x) {
  return (x.x + x.y) + (x.z + x.w);
}

// One fused Sinkhorn iteration, factorized exp-domain.
//   g[n]  = p'[n] / sum_m F[m]*t[n,m],   t = 2^(-SCALE_*C)
//   F[m]  = q'[m] / colsum_raw[m],  colsum_raw = sum_n g[n]*t[n,m]
// cs_prev holds last iteration's colsum_raw (PRE-REDUCED via atomics);
// prologue computes F = q'/cs_prev per column (8 KB/block, no psum scan).
// Epilogue: cross-wave LDS reduce, divide out F (Finv), atomicAdd into
// cs_cur. Each block also zeroes its 32-float slice of cs_nxt (dead
// triple-buffer slot) for the NEXT launch — race-free because launches
// serialize on the stream and nxt != cur != prev.
// V=0: first iter (F==1, reads fp32 C non-temporally, persists u16 T).
// V=1: hot iters (u16 T stream — identical inner loop to R4's proven one).
// V=2: last iter (exact fp32 C, writes g_out).
// Block (b,s): rows [s*32,s*32+32); 4 waves x 8 rows; lane owns cols
// {k*512 + 8*lane + j : k=0..3, j=0..7}.
template <int V>
__global__ __launch_bounds__(256, 4) void sink_iter(
    const float* __restrict__ C, unsigned short* __restrict__ T,
    const float* __restrict__ p, const float* __restrict__ q,
    const float* __restrict__ cs_prev, float* __restrict__ cs_cur,
    float* __restrict__ cs_nxt, float* __restrict__ g_out) {
  __shared__ float lds[4][M_];  // 32 KB
  const int tid = threadIdx.x;
  const int lane = tid & 63, w = tid >> 6;
  const int bid = blockIdx.x;
  const int b = bid >> 6, s = bid & (NCH_ - 1);

  // zero this block's slice of the next launch's accumulator (dead slot)
  if (tid < 32) cs_nxt[bid * 32 + tid] = 0.f;

  f4 lF[8];
  f4 Finv0 = f4{1.f, 1.f, 1.f, 1.f}, Finv1 = f4{1.f, 1.f, 1.f, 1.f};
  if (V == 0) {
#pragma unroll
    for (int k = 0; k < 8; k++) lF[k] = f4{0.f, 0.f, 0.f, 0.f};
  } else {
    const f4* Sp = (const f4*)(cs_prev + (size_t)b * M_);
    const f4* Qp = (const f4*)(q + (size_t)b * M_);
#pragma unroll
    for (int k = 0; k < 4; k++) {
      f4 S0 = Sp[k * 128 + 2 * lane];
      f4 S1 = Sp[k * 128 + 2 * lane + 1];
      f4 q0 = Qp[k * 128 + 2 * lane] + 1e-8f;
      f4 q1 = Qp[k * 128 + 2 * lane + 1] + 1e-8f;
      f4 F0 = q0 / S0;
      f4 F1 = q1 / S1;
      lF[2 * k] = log2v(F0);
      lF[2 * k + 1] = log2v(F1);
      if (k == w) {  // this thread's epilogue columns
        Finv0 = S0 / q0;
        Finv1 = S1 / q1;
      }
    }
  }

  f4 sr[8];
#pragma unroll
  for (int k = 0; k < 8; k++) sr[k] = f4{0.f, 0.f, 0.f, 0.f};

  const int row0 = s * RCH_ + w * 8;
  const float* prow = p + (size_t)b * N_ + row0;

#pragma unroll 2
  for (int i = 0; i < 8; i++) {
    const size_t roff = ((size_t)b * N_ + row0 + i) * (size_t)M_;
    f4 e[8];
    float rs = 0.f;
    if (V == 1) {
      const u16x8* Tr = (const u16x8*)(T + roff);
#pragma unroll
      for (int k = 0; k < 4; k++) {
        u16x8 tt = Tr[k * 64 + lane];
        f4 x0 = lF[2 * k] -
                KQ_ * f4{(float)tt[0], (float)tt[1], (float)tt[2], (float)tt[3]};
        f4 x1 = lF[2 * k + 1] -
                KQ_ * f4{(float)tt[4], (float)tt[5], (float)tt[6], (float)tt[7]};
        e[2 * k] = exp2v(x0);
        e[2 * k + 1] = exp2v(x1);
        rs += hsum(e[2 * k]) + hsum(e[2 * k + 1]);
      }
    } else {
      const f4* Cr = (const f4*)(C + roff);
#pragma unroll
      for (int k = 0; k < 4; k++) {
        f4 c0 = __builtin_nontemporal_load(&Cr[k * 128 + 2 * lane]);
        f4 c1 = __builtin_nontemporal_load(&Cr[k * 128 + 2 * lane + 1]);
        if (V == 0) {  // persist u16 T for hot iterations
          u16x8 o;
          o[0] = (unsigned short)rintf(c0.x * 65535.f);
          o[1] = (unsigned short)rintf(c0.y * 65535.f);
          o[2] = (unsigned short)rintf(c0.z * 65535.f);
          o[3] = (unsigned short)rintf(c0.w * 65535.f);
          o[4] = (unsigned short)rintf(c1.x * 65535.f);
          o[5] = (unsigned short)rintf(c1.y * 65535.f);
          o[6] = (unsigned short)rintf(c1.z * 65535.f);
          o[7] = (unsigned short)rintf(c1.w * 65535.f);
          ((u16x8*)(T + roff))[k * 64 + lane] = o;
        }
        e[2 * k] = exp2v(lF[2 * k] - SCALE_ * c0);
        e[2 * k + 1] = exp2v(lF[2 * k + 1] - SCALE_ * c1);
        rs += hsum(e[2 * k]) + hsum(e[2 * k + 1]);
      }
    }
#pragma unroll
    for (int o = 32; o; o >>= 1) rs += __shfl_xor(rs, o, 64);
    float g = (prow[i] + 1e-8f) / rs;
    if (V == 2 && lane == 0) g_out[(size_t)b * N_ + row0 + i] = g;
#pragma unroll
    for (int k = 0; k < 8; k++) sr[k] += e[k] * g;
  }

  // cross-wave column reduce -> divide out F -> atomic accumulate
#pragma unroll
  for (int k = 0; k < 4; k++) {
    *(f4*)&lds[w][k * 512 + 8 * lane] = sr[2 * k];
    *(f4*)&lds[w][k * 512 + 8 * lane + 4] = sr[2 * k + 1];
  }
  __syncthreads();
  {
    const int base = w * 512 + 8 * lane;
    f4 a0 = *(const f4*)&lds[0][base] + *(const f4*)&lds[1][base] +
            *(const f4*)&lds[2][base] + *(const f4*)&lds[3][base];
    f4 a1 = *(const f4*)&lds[0][base + 4] + *(const f4*)&lds[1][base + 4] +
            *(const f4*)&lds[2][base + 4] + *(const f4*)&lds[3][base + 4];
    a0 *= Finv0;
    a1 *= Finv1;
    float* po = &cs_cur[(size_t)b * M_ + base];
    atomicAdd(po + 0, a0.x);
    atomicAdd(po + 1, a0.y);
    atomicAdd(po + 2, a0.z);
    atomicAdd(po + 3, a0.w);
    atomicAdd(po + 4, a1.x);
    atomicAdd(po + 5, a1.y);
    atomicAdd(po + 6, a1.z);
    atomicAdd(po + 7, a1.w);
  }
}

// Final F: F[m] = q'[m] / colsum_raw[m]
__global__ __launch_bounds__(256) void fin_F(
    const float* __restrict__ cs, const float* __restrict__ q,
    float* __restrict__ F) {
  int gid = blockIdx.x * 256 + threadIdx.x;  // over B_*M_
  F[gid] = (q[gid] + 1e-8f) / cs[gid];
}

// pi = g[n] * F[m] * 2^(-SCALE_*C)  (exact fp32 C)
__global__ __launch_bounds__(256) void pi_kernel(
    const float* __restrict__ C, const float* __restrict__ g_arr,
    const float* __restrict__ F_arr, float* __restrict__ out) {
  int bid = blockIdx.x;
  int tid = threadIdx.x;
  int b = bid >> 11;
  float gg = g_arr[bid];
  const f4* Cr = (const f4*)(C + (size_t)bid * M_);
  const f4* Fr = (const f4*)(F_arr + (size_t)b * M_);
  f4* Or = (f4*)(out + (size_t)bid * M_);
#pragma unroll
  for (int k = 0; k < 2; k++) {
    int i = tid + (k << 8);
    f4 c = __builtin_nontemporal_load(&Cr[i]);
    f4 f = Fr[i];
    f4 r;
    r.x = gg * f.x * exp2f(-SCALE_ * c.x);
    r.y = gg * f.y * exp2f(-SCALE_ * c.y);
    r.z = gg * f.z * exp2f(-SCALE_ * c.z);
    r.w = gg * f.w * exp2f(-SCALE_ * c.w);
    __builtin_nontemporal_store(r, &Or[i]);
  }
}

extern "C" void kernel_launch(void* const* d_in, const int* in_sizes, int n_in,
                              void* d_out, int out_size, void* d_ws, size_t ws_size,
                              hipStream_t stream) {
  const float* p = (const float*)d_in[0];
  const float* q = (const float*)d_in[1];
  const float* C = (const float*)d_in[2];
  float* out = (float*)d_out;

  const size_t Telems = (size_t)B_ * N_ * M_;   // 67.1M u16 = 134 MB
  const size_t fsz = (size_t)B_ * M_;           // 32768 floats
  const size_t gsz = (size_t)B_ * N_;           // 32768 floats
  // ws layout: [g 128KB][F 128KB][cs 3x128KB][T 134MB]
  const size_t small = (gsz + fsz + 3 * fsz) * sizeof(float);  // 640 KB
  const size_t need_all = small + Telems * sizeof(unsigned short);

  float* g_arr = (float*)d_ws;        // proven-safe minimum ws (>=256KB)
  float* F_arr = g_arr + gsz;
  float* cs;
  unsigned short* T;
  if (ws_size >= need_all) {
    cs = F_arr + fsz;
    T = (unsigned short*)(cs + 3 * fsz);
  } else if (ws_size >= small) {
    cs = F_arr + fsz;
    T = (unsigned short*)d_out;       // front 134 MB of out as T scratch
  } else {
    // cs triple-buffer in the tail of d_out (384 KB): last read by fin_F,
    // which completes before pi_kernel rewrites d_out (stream order).
    cs = out + ((size_t)out_size - 3 * fsz);
    T = (unsigned short*)d_out;
  }

  hipMemsetAsync(cs, 0, 3 * fsz * sizeof(float), stream);

  for (int t = 0; t < ITERS_; ++t) {
    const float* prv = cs + (size_t)((t + 2) % 3) * fsz;
    float* cur = cs + (size_t)(t % 3) * fsz;
    float* nxt = cs + (size_t)((t + 1) % 3) * fsz;
    if (t == 0)
      sink_iter<0><<<B_ * NCH_, 256, 0, stream>>>(C, T, p, q, prv, cur, nxt, g_arr);
    else if (t == ITERS_ - 1)
      sink_iter<2><<<B_ * NCH_, 256, 0, stream>>>(C, T, p, q, prv, cur, nxt, g_arr);
    else
      sink_iter<1><<<B_ * NCH_, 256, 0, stream>>>(C, T, p, q, prv, cur, nxt, g_arr);
  }
  fin_F<<<B_ * M_ / 256, 256, 0, stream>>>(cs + (size_t)((ITERS_ - 1) % 3) * fsz,
                                           q, F_arr);
  pi_kernel<<<B_ * N_, 256, 0, stream>>>(C, g_arr, F_arr, out);
}

// Round 10
// 4358.711 us; speedup vs baseline: 2.0318x; 2.0318x over previous
//
#include <hip/hip_runtime.h>
#include <math.h>

#define B_ 16
#define N_ 2048
#define M_ 2048
#define ITERS_ 100
#define RCH_ 64
#define NCH_ (N_ / RCH_)            // 32 chunks
// (1/eps)*log2(e), eps = 0.1
#define SCALE_ 14.426950408889634f
// 12-bit fixed point: c12 = round(C*4095) = 16*hi + lo
#define KH_ (SCALE_ * 16.0f / 4095.0f)
#define KL_ (SCALE_ / 4095.0f)

typedef float f4 __attribute__((ext_vector_type(4)));

static __device__ __forceinline__ f4 exp2v(f4 x) {
  return f4{exp2f(x.x), exp2f(x.y), exp2f(x.z), exp2f(x.w)};
}
static __device__ __forceinline__ float hsum(f4 x) {
  return (x.x + x.y) + (x.z + x.w);
}

__global__ __launch_bounds__(256) void init_kernel(float* __restrict__ lF) {
  lF[blockIdx.x * 256 + threadIdx.x] = 0.f;
}

// One fused Sinkhorn iteration (log-domain factorized, R4-proven):
//   g[n] = p'[n] / rowsum_n,  rowsum_n = sum_m 2^(lF[m] - SCALE_*C[n,m])
//   psum[s][b][m] = sum_{n in chunk s} g[n]*2^(lF[m]-SCALE_*C[n,m])  (F-weighted)
// V=0: first iter — exact fp32 C (NT loads), lF=0, persists u8-hi/u4-lo planes.
// V=1: hot iters  — reads 12-bit planes: x = lF - KH*hi - KL*lo.
// V=2: last iter  — exact fp32 C, writes g_out.
// Block (b,s): rows [s*64,s*64+64); 4 waves x 16 rows; lane owns cols
// {k*512 + 8*lane + j : k=0..3, j=0..7}.
template <int V>
__global__ __launch_bounds__(256, 2) void sink_iter(
    const float* __restrict__ C, unsigned char* __restrict__ T8,
    unsigned char* __restrict__ T4, const float* __restrict__ p,
    const float* __restrict__ lF_arr, float* __restrict__ psum,
    float* __restrict__ g_out) {
  __shared__ float lds[4][M_];  // 32 KB
  const int tid = threadIdx.x;
  const int lane = tid & 63, w = tid >> 6;
  const int bid = blockIdx.x;
  const int b = bid >> 5, s = bid & (NCH_ - 1);

  f4 lF[8];
  if (V == 0) {
#pragma unroll
    for (int k = 0; k < 8; k++) lF[k] = f4{0.f, 0.f, 0.f, 0.f};
  } else {
    const f4* L = (const f4*)(lF_arr + (size_t)b * M_);
#pragma unroll
    for (int k = 0; k < 4; k++) {
      lF[2 * k] = L[k * 128 + 2 * lane];
      lF[2 * k + 1] = L[k * 128 + 2 * lane + 1];
    }
  }

  f4 sr[8];
#pragma unroll
  for (int k = 0; k < 8; k++) sr[k] = f4{0.f, 0.f, 0.f, 0.f};

  const int row0 = s * RCH_ + w * 16;
  const float* prow = p + (size_t)b * N_ + row0;

#pragma unroll 2
  for (int i = 0; i < 16; i++) {
    const size_t roff = ((size_t)b * N_ + row0 + i) * (size_t)M_;
    f4 e[8];
    float rs = 0.f;
    if (V == 1) {
      const uint2* H = (const uint2*)(T8 + roff);
      const unsigned int* Lo = (const unsigned int*)(T4 + roff / 2);
#pragma unroll
      for (int k = 0; k < 4; k++) {
        uint2 hh = H[k * 64 + lane];
        unsigned int nb = Lo[k * 64 + lane];
        f4 fh0 = f4{(float)(hh.x & 255u), (float)((hh.x >> 8) & 255u),
                    (float)((hh.x >> 16) & 255u), (float)(hh.x >> 24)};
        f4 fh1 = f4{(float)(hh.y & 255u), (float)((hh.y >> 8) & 255u),
                    (float)((hh.y >> 16) & 255u), (float)(hh.y >> 24)};
        f4 fl0 = f4{(float)(nb & 15u), (float)((nb >> 4) & 15u),
                    (float)((nb >> 8) & 15u), (float)((nb >> 12) & 15u)};
        f4 fl1 = f4{(float)((nb >> 16) & 15u), (float)((nb >> 20) & 15u),
                    (float)((nb >> 24) & 15u), (float)(nb >> 28)};
        f4 x0 = lF[2 * k] - KH_ * fh0 - KL_ * fl0;
        f4 x1 = lF[2 * k + 1] - KH_ * fh1 - KL_ * fl1;
        e[2 * k] = exp2v(x0);
        e[2 * k + 1] = exp2v(x1);
        rs += hsum(e[2 * k]) + hsum(e[2 * k + 1]);
      }
    } else {
      const f4* Cr = (const f4*)(C + roff);
#pragma unroll
      for (int k = 0; k < 4; k++) {
        f4 c0 = __builtin_nontemporal_load(&Cr[k * 128 + 2 * lane]);
        f4 c1 = __builtin_nontemporal_load(&Cr[k * 128 + 2 * lane + 1]);
        if (V == 0) {  // persist 12-bit planes for hot iterations
          unsigned int q0 = (unsigned int)rintf(c0.x * 4095.f);
          unsigned int q1 = (unsigned int)rintf(c0.y * 4095.f);
          unsigned int q2 = (unsigned int)rintf(c0.z * 4095.f);
          unsigned int q3 = (unsigned int)rintf(c0.w * 4095.f);
          unsigned int q4 = (unsigned int)rintf(c1.x * 4095.f);
          unsigned int q5 = (unsigned int)rintf(c1.y * 4095.f);
          unsigned int q6 = (unsigned int)rintf(c1.z * 4095.f);
          unsigned int q7 = (unsigned int)rintf(c1.w * 4095.f);
          uint2 hh;
          hh.x = (q0 >> 4) | ((q1 >> 4) << 8) | ((q2 >> 4) << 16) |
                 ((q3 >> 4) << 24);
          hh.y = (q4 >> 4) | ((q5 >> 4) << 8) | ((q6 >> 4) << 16) |
                 ((q7 >> 4) << 24);
          unsigned int nb = (q0 & 15u) | ((q1 & 15u) << 4) |
                            ((q2 & 15u) << 8) | ((q3 & 15u) << 12) |
                            ((q4 & 15u) << 16) | ((q5 & 15u) << 20) |
                            ((q6 & 15u) << 24) | ((q7 & 15u) << 28);
          ((uint2*)(T8 + roff))[k * 64 + lane] = hh;
          ((unsigned int*)(T4 + roff / 2))[k * 64 + lane] = nb;
        }
        e[2 * k] = exp2v(lF[2 * k] - SCALE_ * c0);
        e[2 * k + 1] = exp2v(lF[2 * k + 1] - SCALE_ * c1);
        rs += hsum(e[2 * k]) + hsum(e[2 * k + 1]);
      }
    }
#pragma unroll
    for (int o = 32; o; o >>= 1) rs += __shfl_xor(rs, o, 64);
    float g = (prow[i] + 1e-8f) / rs;
    if (V == 2 && lane == 0) g_out[(size_t)b * N_ + row0 + i] = g;
#pragma unroll
    for (int k = 0; k < 8; k++) sr[k] += e[k] * g;
  }

  // cross-wave column reduction -> psum (F-weighted colsums)
#pragma unroll
  for (int k = 0; k < 4; k++) {
    *(f4*)&lds[w][k * 512 + 8 * lane] = sr[2 * k];
    *(f4*)&lds[w][k * 512 + 8 * lane + 4] = sr[2 * k + 1];
  }
  __syncthreads();
  {
    const int base = w * 512 + 8 * lane;
    f4 a0 = *(const f4*)&lds[0][base] + *(const f4*)&lds[1][base] +
            *(const f4*)&lds[2][base] + *(const f4*)&lds[3][base];
    f4 a1 = *(const f4*)&lds[0][base + 4] + *(const f4*)&lds[1][base + 4] +
            *(const f4*)&lds[2][base + 4] + *(const f4*)&lds[3][base + 4];
    float* po = &psum[(size_t)(s * B_ + b) * M_ + base];
    *(f4*)po = a0;
    *(f4*)(po + 4) = a1;
  }
}

// lF update (log-domain, multiplicative — psum includes F):
//   lF_new = lF_old + log2(q' / sum_s psum)
__global__ __launch_bounds__(256) void lfk_kernel(
    const float* __restrict__ psum, const float* __restrict__ q,
    float* __restrict__ lF) {
  int gid = blockIdx.x * 256 + threadIdx.x;  // b*M_ + m
  int b = gid >> 11;
  int m = gid & (M_ - 1);
  float S = 0.f;
#pragma unroll 8
  for (int s = 0; s < NCH_; s++)
    S += psum[(size_t)(s * B_ + b) * M_ + m];
  lF[gid] += log2f((q[gid] + 1e-8f) / S);
}

// pi = g[n] * 2^(lF[m] - SCALE_*C)  (exact fp32 C)
__global__ __launch_bounds__(256) void pi_kernel(
    const float* __restrict__ C, const float* __restrict__ g_arr,
    const float* __restrict__ lF_arr, float* __restrict__ out) {
  int bid = blockIdx.x;
  int tid = threadIdx.x;
  int b = bid >> 11;
  float gg = g_arr[bid];
  const f4* Cr = (const f4*)(C + (size_t)bid * M_);
  const f4* Lr = (const f4*)(lF_arr + (size_t)b * M_);
  f4* Or = (f4*)(out + (size_t)bid * M_);
#pragma unroll
  for (int k = 0; k < 2; k++) {
    int i = tid + (k << 8);
    f4 c = __builtin_nontemporal_load(&Cr[i]);
    f4 L = Lr[i];
    f4 r;
    r.x = gg * exp2f(fmaf(-SCALE_, c.x, L.x));
    r.y = gg * exp2f(fmaf(-SCALE_, c.y, L.y));
    r.z = gg * exp2f(fmaf(-SCALE_, c.z, L.z));
    r.w = gg * exp2f(fmaf(-SCALE_, c.w, L.w));
    __builtin_nontemporal_store(r, &Or[i]);
  }
}

extern "C" void kernel_launch(void* const* d_in, const int* in_sizes, int n_in,
                              void* d_out, int out_size, void* d_ws, size_t ws_size,
                              hipStream_t stream) {
  const float* p = (const float*)d_in[0];
  const float* q = (const float*)d_in[1];
  const float* C = (const float*)d_in[2];
  float* out = (float*)d_out;

  const size_t Telems = (size_t)B_ * N_ * M_;     // 67,108,864
  const size_t t8b = Telems;                      // 67.1 MB
  const size_t t4b = Telems / 2;                  // 33.6 MB
  const size_t psz = (size_t)NCH_ * B_ * M_;      // 1,048,576 floats = 4 MB
  const size_t gsz = (size_t)B_ * N_;
  const size_t fsz = (size_t)B_ * M_;
  const size_t need_all = t8b + t4b + (psz + gsz + fsz) * sizeof(float);

  unsigned char *T8, *T4;
  float *psum, *g_arr, *lF;
  if (ws_size >= need_all) {
    T8 = (unsigned char*)d_ws;
    T4 = T8 + t8b;
    psum = (float*)(T4 + t4b);
    g_arr = psum + psz;
    lF = g_arr + gsz;
  } else {
    // g,lF in ws (256 KB); planes in d_out front (100.7 MB), psum in d_out
    // tail (4 MB). Planes last read at t=98, psum last read by the final
    // lfk; pi_kernel then rewrites all of d_out reading only C/g/lF ->
    // safe and deterministic (no cross-call state).
    g_arr = (float*)d_ws;
    lF = g_arr + gsz;
    T8 = (unsigned char*)d_out;
    T4 = T8 + t8b;
    psum = out + ((size_t)out_size - psz);
  }

  init_kernel<<<(B_ * M_) / 256, 256, 0, stream>>>(lF);

  for (int t = 0; t < ITERS_; ++t) {
    if (t == 0)
      sink_iter<0><<<B_ * NCH_, 256, 0, stream>>>(C, T8, T4, p, lF, psum, g_arr);
    else if (t == ITERS_ - 1)
      sink_iter<2><<<B_ * NCH_, 256, 0, stream>>>(C, T8, T4, p, lF, psum, g_arr);
    else
      sink_iter<1><<<B_ * NCH_, 256, 0, stream>>>(C, T8, T4, p, lF, psum, g_arr);
    lfk_kernel<<<(B_ * M_) / 256, 256, 0, stream>>>(psum, q, lF);
  }
  pi_kernel<<<B_ * N_, 256, 0, stream>>>(C, g_arr, lF, out);
}